// Round 1
// baseline (1191.457 us; speedup 1.0000x reference)
//
#include <hip/hip_runtime.h>
#include <cstdint>
#include <cstddef>

// Problem constants (B,S,HID,NH,IM,E fixed by the reference)
#define B_    4
#define S_    2048
#define HID_  1024
#define NH_   4
#define HD_   256     // HID/NH
#define IM_   2048
#define E_    4
#define M_    8192    // B_*S_ tokens
#define NHG_  4       // heads per attention group

typedef __bf16 bf16x8 __attribute__((ext_vector_type(8)));
typedef float  f32x4  __attribute__((ext_vector_type(4)));

__device__ __forceinline__ unsigned short f32_to_bf16(float f) {
  unsigned int u = __float_as_uint(f);
  u += 0x7fffu + ((u >> 16) & 1u);   // round-to-nearest-even
  return (unsigned short)(u >> 16);
}

// async 16B global->LDS DMA (global_load_lds_dwordx4). LDS dest is
// wave-uniform base + lane*16 -> LDS layout contiguous in lane order.
__device__ __forceinline__ void gload16(const unsigned short* g, unsigned short* l) {
  __builtin_amdgcn_global_load_lds(
      (const __attribute__((address_space(1))) void*)g,
      (__attribute__((address_space(3))) void*)l, 16, 0, 0);
}

// XCD-aware swizzle: contiguous y-bands per XCD.
__device__ __forceinline__ void swizzle_xy(int& bx, int& by) {
  const int gx = gridDim.x, gy = gridDim.y;
  const int flat = blockIdx.x + blockIdx.y * gx;
  const int xcd = flat & 7, i = flat >> 3;
  const int rpx = gy >> 3;          // y-rows per XCD
  bx = i % gx;
  by = xcd * rpx + i / gx;
}

// ---------------- epilogue variants (generic single-B GEMM) ----------------
#define EPI_F32      0   // C fp32 (attention scores), batched via strideCz
#define EPI_VT       2   // write V^T [b][h][d][s] bf16
#define EPI_PV_O     3   // write attn O into [token][h*HD+n] bf16
#define EPI_WO       4   // out2 = add_src + acc  (h1 into d_out)
#define EPI_DOWN     5   // out2 += acc  (fallback path)

struct EpiAux {
  float* c_f32;
  unsigned short* c_bf16;
  const float* add_src;       // hidden (WO)
  float* out2;                // d_out (WO/DOWN)
  long long strideCz;
  int ldc;
};

// Generic batched GEMM: C[z] = A[z] (MxK, row-major, lda) @ B[z]^T.
// 128x128 tile, BK=32, 4 waves x (4x4) 16x16x32 bf16 MFMA fragments.
// Double-buffered LDS, one-iteration-ahead async global_load_lds prefetch.
template<int EPI>
__global__ __launch_bounds__(256) void gemm_bf16k(
    const unsigned short* __restrict__ A, int lda, long long sAo, long long sAi, int zbA,
    const unsigned short* __restrict__ B, int ldb, long long sBo, long long sBi, int zbB,
    int zshift, int zmask, int zbC, int K, EpiAux aux)
{
  __shared__ unsigned short As[2][128 * 32];
  __shared__ unsigned short Bs[2][128 * 32];

  const int t = threadIdx.x;
  int bx, by;
  swizzle_xy(bx, by);
  const int m0 = by * 128, n0 = bx * 128;
  const int z  = blockIdx.z;
  const int zA = z + zbA, zB = z + zbB, zC = z + zbC;
  const unsigned short* Ab = A + (long long)(zA >> zshift) * sAo + (long long)(zA & zmask) * sAi;
  const unsigned short* Bb = B + (long long)(zB >> zshift) * sBo + (long long)(zB & zmask) * sBi;

  const int lane = t & 63, wave = t >> 6;
  const int wm = (wave >> 1) * 64, wn = (wave & 1) * 64;
  const int lrow = lane & 15, quad = lane >> 4;

  f32x4 acc[4][4] = {};

  const int srow = lane >> 2;         // 0..15
  const int sko  = (lane & 3) * 8;    // k-elem 0/8/16/24
  const unsigned short* aRow0 = Ab + (long long)(m0 + wave * 16       + srow) * lda + sko;
  const unsigned short* aRow1 = Ab + (long long)(m0 + (wave + 4) * 16 + srow) * lda + sko;
  const unsigned short* bRow0 = Bb + (long long)(n0 + wave * 16       + srow) * ldb + sko;
  const unsigned short* bRow1 = Bb + (long long)(n0 + (wave + 4) * 16 + srow) * ldb + sko;
  const int dst0 = (wave * 16) * 32, dst1 = ((wave + 4) * 16) * 32;

  gload16(aRow0, &As[0][dst0]);
  gload16(aRow1, &As[0][dst1]);
  gload16(bRow0, &Bs[0][dst0]);
  gload16(bRow1, &Bs[0][dst1]);

  int cur = 0;
  for (int kk = 0; kk < K; kk += 32, cur ^= 1) {
    __syncthreads();
    if (kk + 32 < K) {
      const int nxt = cur ^ 1, k2 = kk + 32;
      gload16(aRow0 + k2, &As[nxt][dst0]);
      gload16(aRow1 + k2, &As[nxt][dst1]);
      gload16(bRow0 + k2, &Bs[nxt][dst0]);
      gload16(bRow1 + k2, &Bs[nxt][dst1]);
    }
    bf16x8 af[4], bfr[4];
    #pragma unroll
    for (int i = 0; i < 4; ++i) {
      af[i]  = *reinterpret_cast<const bf16x8*>(&As[cur][(wm + i * 16 + lrow) * 32 + quad * 8]);
      bfr[i] = *reinterpret_cast<const bf16x8*>(&Bs[cur][(wn + i * 16 + lrow) * 32 + quad * 8]);
    }
    #pragma unroll
    for (int i = 0; i < 4; ++i)
      #pragma unroll
      for (int j = 0; j < 4; ++j)
        acc[i][j] = __builtin_amdgcn_mfma_f32_16x16x32_bf16(af[i], bfr[j], acc[i][j], 0, 0, 0);
  }

  // epilogue: D row = quad*4+r, col = lane&15
  #pragma unroll
  for (int mi = 0; mi < 4; ++mi) {
    #pragma unroll
    for (int ni = 0; ni < 4; ++ni) {
      #pragma unroll
      for (int r = 0; r < 4; ++r) {
        const int gm = m0 + wm + mi * 16 + quad * 4 + r;
        const int gn = n0 + wn + ni * 16 + lrow;
        const float val = acc[mi][ni][r];
        if (EPI == EPI_F32) {
          aux.c_f32[(long long)zC * aux.strideCz + (long long)gm * aux.ldc + gn] = val;
        } else if (EPI == EPI_VT) {
          const int b = gm >> 11, s = gm & (S_ - 1);
          const int h = gn >> 8, d = gn & (HD_ - 1);
          aux.c_bf16[((long long)(b * NH_ + h) * HD_ + d) * S_ + s] = f32_to_bf16(val);
        } else if (EPI == EPI_PV_O) {
          const int b = zC >> 2, h = zC & (NH_ - 1);
          aux.c_bf16[((long long)(b * S_ + gm)) * HID_ + h * HD_ + gn] = f32_to_bf16(val);
        } else if (EPI == EPI_WO) {
          const long long idx = (long long)gm * HID_ + gn;
          aux.out2[idx] = val + aux.add_src[idx];
        } else if (EPI == EPI_DOWN) {
          const long long idx = (long long)gm * HID_ + gn;
          aux.out2[idx] += val;
        }
      }
    }
  }
}

// ---- dual-B GEMM (shared A staging, two accumulator sets, 32 MFMA/barrier)
// __launch_bounds__(256, 2) is LOAD-BEARING: without the 2-waves/EU floor the
// allocator uses ~280 regs/wave (incl AGPR) -> 1 block/CU -> collapse.
#define EPI2_QK 0   // out0 = bf16(elu(accq)+1), out1 = bf16(elu(acck)+1)
#define EPI2_GU 1   // out0 = bf16(silu(g)*u*rw[token][zb]), ldc=IM_ (fallback)

template<int EPI2>
__global__ __launch_bounds__(256, 2) void gemm_dual_k(
    const unsigned short* __restrict__ A,      // [M_][HID_]
    const unsigned short* __restrict__ B0b,    // B0 [*][HID_]
    const unsigned short* __restrict__ B1b,    // B1 [*][HID_]
    int zb,
    unsigned short* __restrict__ out0, unsigned short* __restrict__ out1,
    const float* __restrict__ rw)
{
  __shared__ unsigned short As[2][128 * 32];
  __shared__ unsigned short B0s[2][128 * 32];
  __shared__ unsigned short B1s[2][128 * 32];

  const int t = threadIdx.x;
  int bx, by;
  swizzle_xy(bx, by);
  const int m0 = by * 128, n0 = bx * 128;

  const int lane = t & 63, wave = t >> 6;
  const int wm = (wave >> 1) * 64, wn = (wave & 1) * 64;
  const int lrow = lane & 15, quad = lane >> 4;

  f32x4 acc0[4][4] = {}, acc1[4][4] = {};

  const int srow = lane >> 2;
  const int sko  = (lane & 3) * 8;
  const unsigned short* aRow0 = A   + (long long)(m0 + wave * 16       + srow) * HID_ + sko;
  const unsigned short* aRow1 = A   + (long long)(m0 + (wave + 4) * 16 + srow) * HID_ + sko;
  const unsigned short* gRow0 = B0b + (long long)(n0 + wave * 16       + srow) * HID_ + sko;
  const unsigned short* gRow1 = B0b + (long long)(n0 + (wave + 4) * 16 + srow) * HID_ + sko;
  const unsigned short* uRow0 = B1b + (long long)(n0 + wave * 16       + srow) * HID_ + sko;
  const unsigned short* uRow1 = B1b + (long long)(n0 + (wave + 4) * 16 + srow) * HID_ + sko;
  const int dst0 = (wave * 16) * 32, dst1 = ((wave + 4) * 16) * 32;

  gload16(aRow0, &As[0][dst0]);
  gload16(aRow1, &As[0][dst1]);
  gload16(gRow0, &B0s[0][dst0]);
  gload16(gRow1, &B0s[0][dst1]);
  gload16(uRow0, &B1s[0][dst0]);
  gload16(uRow1, &B1s[0][dst1]);

  int cur = 0;
  for (int kk = 0; kk < HID_; kk += 32, cur ^= 1) {
    __syncthreads();
    if (kk + 32 < HID_) {
      const int nxt = cur ^ 1, k2 = kk + 32;
      gload16(aRow0 + k2, &As[nxt][dst0]);
      gload16(aRow1 + k2, &As[nxt][dst1]);
      gload16(gRow0 + k2, &B0s[nxt][dst0]);
      gload16(gRow1 + k2, &B0s[nxt][dst1]);
      gload16(uRow0 + k2, &B1s[nxt][dst0]);
      gload16(uRow1 + k2, &B1s[nxt][dst1]);
    }
    bf16x8 af[4], b0[4], b1[4];
    #pragma unroll
    for (int i = 0; i < 4; ++i) {
      af[i] = *reinterpret_cast<const bf16x8*>(&As[cur][(wm + i * 16 + lrow) * 32 + quad * 8]);
      b0[i] = *reinterpret_cast<const bf16x8*>(&B0s[cur][(wn + i * 16 + lrow) * 32 + quad * 8]);
      b1[i] = *reinterpret_cast<const bf16x8*>(&B1s[cur][(wn + i * 16 + lrow) * 32 + quad * 8]);
    }
    #pragma unroll
    for (int i = 0; i < 4; ++i)
      #pragma unroll
      for (int j = 0; j < 4; ++j) {
        acc0[i][j] = __builtin_amdgcn_mfma_f32_16x16x32_bf16(af[i], b0[j], acc0[i][j], 0, 0, 0);
        acc1[i][j] = __builtin_amdgcn_mfma_f32_16x16x32_bf16(af[i], b1[j], acc1[i][j], 0, 0, 0);
      }
  }

  #pragma unroll
  for (int mi = 0; mi < 4; ++mi)
    #pragma unroll
    for (int r = 0; r < 4; ++r) {
      const int gm = m0 + wm + mi * 16 + quad * 4 + r;
      float rwv = 0.f;
      if (EPI2 == EPI2_GU) rwv = rw[(long long)gm * E_ + zb];
      #pragma unroll
      for (int ni = 0; ni < 4; ++ni) {
        const int gn = n0 + wn + ni * 16 + lrow;
        const float v0 = acc0[mi][ni][r];
        const float v1 = acc1[mi][ni][r];
        if (EPI2 == EPI2_QK) {
          const float eq = v0 > 0.f ? v0 + 1.f : __expf(v0);
          const float ek = v1 > 0.f ? v1 + 1.f : __expf(v1);
          out0[(long long)gm * HID_ + gn] = f32_to_bf16(eq);
          out1[(long long)gm * HID_ + gn] = f32_to_bf16(ek);
        } else {  // EPI2_GU
          const float sg = v0 / (1.f + __expf(-v0));      // silu(gate)
          out0[(long long)gm * IM_ + gn] = f32_to_bf16(sg * v1 * rwv);
        }
      }
    }
}

// ======================= 8-phase 256-class GEMM (m201 port) =================
// C = A (MxK) @ B^T (NxK), bf16 in, fp32 acc. BM x 256 tile, BK=64, 8 waves
// (2M x 4N), 1 block/CU. Per K-tile: 4 phases, each {ds_read frag subset;
// stage 1 half-tile via global_load_lds; barrier; lgkmcnt(0); setprio(1);
// MFRAG*2 MFMA; setprio(0); barrier}. Counted vmcnt (4 or 2) ONCE per K-tile,
// never 0 in the main loop (T3+T4). LDS XOR-swizzle (row&7)<<4 applied on the
// pre-swizzled GLOBAL source (global_load_lds writes linearly) and on the
// ds_read address (T2, both-sides-or-neither rule).
// Phase schedule (tile T, buf c):
//   ph1: read A[kk0]+B[ns0,kk0]; stage (T+1).B.h0 -> buf c^1; MFMA(ns0,kk0)
//   ph2: read A[kk1]+B[ns1,kk0]; stage (T+1).B.h1 -> buf c^1; MFMA(ns1,kk0)
//   ph3: read B[ns0,kk1];        stage (T+2).A.h0 -> buf c;   MFMA(ns0,kk1)
//   ph4: read B[ns1,kk1];        stage (T+2).A.h1 -> buf c; vmcnt; MFMA(ns1,kk1)
// Safety: A reads drain by ph2 barrier (A slots overwritten ph3/4); B reads
// drain by ph4 barrier (B slots overwritten next tile's ph1/2).
#define EPI8_U    0   // o_bf = bf16(acc)
#define EPI8_GATE 1   // o_bf = bf16(silu(acc) * u_in * rw[token][expert])
#define EPI8_DOWN 2   // o_f32 += acc
template<int BM, int EPI, int KTOT, int KROW, bool PAIRK>
__global__ __launch_bounds__(512, 2) void gemm8p_k(
    const unsigned short* A0, const unsigned short* A1,
    const unsigned short* B0, const unsigned short* B1,
    const unsigned short* u_in, const float* __restrict__ rw, int expert,
    unsigned short* o_bf, float* o_f32, int ldo)
{
  constexpr int MFRAG  = BM / 32;        // per-wave m-frags
  constexpr int AELEM  = BM * 64;        // elems per A buffer
  constexpr int BELEM  = 256 * 64;       // elems per B buffer
  constexpr int AUNITS = BM / 128;       // A half-tiles per K-tile (2 or 1)
  constexpr int NUNITS = AUNITS + 2;     // + 2 B half-tiles
  constexpr int NT     = KTOT / 64;      // K-tiles (even)
  constexpr int NT2    = NT / 2;         // PAIRK boundary

  __shared__ unsigned short smem[2 * AELEM + 2 * BELEM];

  const int t = threadIdx.x;
  const int wave = t >> 6, lane = t & 63;
  const int lrow = lane & 15, quad = lane >> 4;
  const int wrow0 = (wave >> 2) * (BM / 2);
  const int wcol0 = (wave & 3) * 64;

  int bx, by;
  swizzle_xy(bx, by);
  const int m0 = by * BM, n0 = bx * 256;

  // -------- staging geometry (per-thread constants) --------
  const int r8   = lane >> 3;                       // 0..7 row-in-segment
  const int cswz = ((lane & 7) ^ r8) << 4;          // swizzled byte col
  const int riu0 = wave * 16 + r8;                  // row-in-unit, call i=0
  const unsigned short* gA0[2]; const unsigned short* gA1[2];
  const unsigned short* gB0[2]; const unsigned short* gB1[2];
  #pragma unroll
  for (int i = 0; i < 2; ++i) {
    const int riu = riu0 + i * 8;
    gA0[i] = (const unsigned short*)((const char*)(A0 + (size_t)(m0 + riu) * KROW) + cswz);
    gB0[i] = (const unsigned short*)((const char*)(B0 + (size_t)(n0 + riu) * KROW) + cswz);
    if (PAIRK) {
      gA1[i] = (const unsigned short*)((const char*)(A1 + (size_t)(m0 + riu) * KROW) + cswz);
      gB1[i] = (const unsigned short*)((const char*)(B1 + (size_t)(n0 + riu) * KROW) + cswz);
    } else { gA1[i] = nullptr; gB1[i] = nullptr; }
  }

  auto stage = [&](int kt, int unit, int buf) {
    int ktl = kt;
    bool hi = false;
    if (PAIRK && kt >= NT2) { ktl = kt - NT2; hi = true; }
    const bool isA = unit < AUNITS;
    const int  uh  = isA ? unit : unit - AUNITS;
    #pragma unroll
    for (int i = 0; i < 2; ++i) {
      const unsigned short* src = isA ? (hi ? gA1[i] : gA0[i]) : (hi ? gB1[i] : gB0[i]);
      src += (size_t)uh * 128 * KROW + ktl * 64;
      unsigned short* dst = &smem[(isA ? buf * AELEM : 2 * AELEM + buf * BELEM)
                                  + uh * 8192 + wave * 1024 + i * 512];
      gload16(src, dst);
    }
  };

  // -------- fragment reads (swizzled ds_read_b128) --------
  const int xr = (lane & 7) << 4;
  auto readA = [&](bf16x8* o, int buf, int kk) {
    const char* base = (const char*)&smem[buf * AELEM];
    #pragma unroll
    for (int mi = 0; mi < MFRAG; ++mi) {
      const int row = wrow0 + mi * 16 + lrow;
      o[mi] = *(const bf16x8*)(base + row * 128 + ((kk * 64 + quad * 16) ^ xr));
    }
  };
  auto readB = [&](bf16x8* o, int buf, int ns, int kk) {
    const char* base = (const char*)&smem[2 * AELEM + buf * BELEM];
    #pragma unroll
    for (int nj = 0; nj < 2; ++nj) {
      const int row = wcol0 + (ns * 2 + nj) * 16 + lrow;
      o[nj] = *(const bf16x8*)(base + row * 128 + ((kk * 64 + quad * 16) ^ xr));
    }
  };

  f32x4 acc[MFRAG][4] = {};
  auto mm = [&](const bf16x8* aF, const bf16x8* bF, int ns) {
    #pragma unroll
    for (int mi = 0; mi < MFRAG; ++mi)
      #pragma unroll
      for (int nj = 0; nj < 2; ++nj)
        acc[mi][ns * 2 + nj] =
            __builtin_amdgcn_mfma_f32_16x16x32_bf16(aF[mi], bF[nj], acc[mi][ns * 2 + nj], 0, 0, 0);
  };

  // -------- prologue: T0 fully, T1's A unit(s); counted wait --------
  #pragma unroll
  for (int u = 0; u < NUNITS; ++u) stage(0, u, 0);
  #pragma unroll
  for (int u = 0; u < AUNITS; ++u) stage(1, u, 1);
  if (AUNITS == 2) { asm volatile("s_waitcnt vmcnt(4)" ::: "memory"); }
  else             { asm volatile("s_waitcnt vmcnt(2)" ::: "memory"); }
  __builtin_amdgcn_s_barrier();

  auto tile4 = [&](int T, int c) {
    bf16x8 a0[MFRAG], a1[MFRAG], bF[2];
    // ---- phase 1 ----
    readA(a0, c, 0);
    readB(bF, c, 0, 0);
    if (T + 1 < NT) stage(T + 1, AUNITS, c ^ 1);
    __builtin_amdgcn_s_barrier();
    asm volatile("s_waitcnt lgkmcnt(0)" ::: "memory");
    __builtin_amdgcn_s_setprio(1);
    mm(a0, bF, 0);
    __builtin_amdgcn_s_setprio(0);
    __builtin_amdgcn_s_barrier();
    // ---- phase 2 ----
    readA(a1, c, 1);
    readB(bF, c, 1, 0);
    if (T + 1 < NT) stage(T + 1, AUNITS + 1, c ^ 1);
    __builtin_amdgcn_s_barrier();
    asm volatile("s_waitcnt lgkmcnt(0)" ::: "memory");
    __builtin_amdgcn_s_setprio(1);
    mm(a0, bF, 1);
    __builtin_amdgcn_s_setprio(0);
    __builtin_amdgcn_s_barrier();
    // ---- phase 3 ----
    readB(bF, c, 0, 1);
    if (T + 2 < NT) stage(T + 2, 0, c);
    __builtin_amdgcn_s_barrier();
    asm volatile("s_waitcnt lgkmcnt(0)" ::: "memory");
    __builtin_amdgcn_s_setprio(1);
    mm(a1, bF, 0);
    __builtin_amdgcn_s_setprio(0);
    __builtin_amdgcn_s_barrier();
    // ---- phase 4 ----
    readB(bF, c, 1, 1);
    if (AUNITS == 2 && T + 2 < NT) stage(T + 2, 1, c);
    if (AUNITS == 2) { asm volatile("s_waitcnt vmcnt(4)" ::: "memory"); }
    else             { asm volatile("s_waitcnt vmcnt(2)" ::: "memory"); }
    __builtin_amdgcn_s_barrier();
    asm volatile("s_waitcnt lgkmcnt(0)" ::: "memory");
    __builtin_amdgcn_s_setprio(1);
    mm(a1, bF, 1);
    __builtin_amdgcn_s_setprio(0);
    __builtin_amdgcn_s_barrier();
  };

  for (int T = 0; T < NT; T += 2) {
    tile4(T, 0);
    tile4(T + 1, 1);
  }

  // -------- epilogue --------
  #pragma unroll
  for (int mi = 0; mi < MFRAG; ++mi) {
    #pragma unroll
    for (int r = 0; r < 4; ++r) {
      const int gm = m0 + wrow0 + mi * 16 + quad * 4 + r;
      float rwv = 0.f;
      if (EPI == EPI8_GATE) rwv = rw[(size_t)gm * E_ + expert];
      #pragma unroll
      for (int nj = 0; nj < 4; ++nj) {
        const int gn = n0 + wcol0 + nj * 16 + lrow;
        const float v = acc[mi][nj][r];
        const size_t idx = (size_t)gm * ldo + gn;
        if (EPI == EPI8_U) {
          o_bf[idx] = f32_to_bf16(v);
        } else if (EPI == EPI8_GATE) {
          const float uf = __uint_as_float((unsigned)u_in[idx] << 16);
          const float sg = v / (1.f + __expf(-v));
          o_bf[idx] = f32_to_bf16(sg * uf * rwv);
        } else {  // EPI8_DOWN
          o_f32[idx] += v;
        }
      }
    }
  }
}

// fp32 [R][C] -> bf16 [C][R]; z selects among 4 sources, dst stride R*C
__global__ void transpose_cast4_k(const float* s0, const float* s1,
                                  const float* s2, const float* s3,
                                  unsigned short* __restrict__ out, int R, int C)
{
  __shared__ float tile[32][33];
  const int z = blockIdx.z;
  const float* in = (z == 0) ? s0 : (z == 1) ? s1 : (z == 2) ? s2 : s3;
  unsigned short* o = out + (long long)z * R * C;
  const int c0 = blockIdx.x * 32, r0 = blockIdx.y * 32;
  const int tx = threadIdx.x, ty = threadIdx.y;
  #pragma unroll
  for (int i = 0; i < 32; i += 8)
    tile[ty + i][tx] = in[(long long)(r0 + ty + i) * C + c0 + tx];
  __syncthreads();
  #pragma unroll
  for (int i = 0; i < 32; i += 8)
    o[(long long)(c0 + ty + i) * R + r0 + tx] = f32_to_bf16(tile[tx][ty + i]);
}

// fp32 [R][C] -> bf16 [C][R]; z<4: srcA/dstA expert z; z>=4: srcB/dstB
__global__ void transpose_cast2x4_k(const float* __restrict__ sA,
                                    const float* __restrict__ sB,
                                    unsigned short* __restrict__ dA,
                                    unsigned short* __restrict__ dB,
                                    int R, int C)
{
  __shared__ float tile[32][33];
  const int z = blockIdx.z;
  const long long eo = (long long)(z & 3) * R * C;
  const float* in = ((z < 4) ? sA : sB) + eo;
  unsigned short* o = ((z < 4) ? dA : dB) + eo;
  const int c0 = blockIdx.x * 32, r0 = blockIdx.y * 32;
  const int tx = threadIdx.x, ty = threadIdx.y;
  #pragma unroll
  for (int i = 0; i < 32; i += 8)
    tile[ty + i][tx] = in[(long long)(r0 + ty + i) * C + c0 + tx];
  __syncthreads();
  #pragma unroll
  for (int i = 0; i < 32; i += 8)
    o[(long long)(c0 + ty + i) * R + r0 + tx] = f32_to_bf16(tile[tx][ty + i]);
}

// fp32 [R][C] -> bf16 [C][R], batched over z (single base, stride R*C)
__global__ void transpose_cast_k(const float* __restrict__ in,
                                 unsigned short* __restrict__ out, int R, int C)
{
  __shared__ float tile[32][33];
  const long long bo = (long long)blockIdx.z * R * C;
  const int c0 = blockIdx.x * 32, r0 = blockIdx.y * 32;
  const int tx = threadIdx.x, ty = threadIdx.y;
  #pragma unroll
  for (int i = 0; i < 32; i += 8)
    tile[ty + i][tx] = in[bo + (long long)(r0 + ty + i) * C + c0 + tx];
  __syncthreads();
  #pragma unroll
  for (int i = 0; i < 32; i += 8)
    out[bo + (long long)(c0 + ty + i) * R + r0 + tx] = f32_to_bf16(tile[tx][ty + i]);
}

// rmsnorm row (HID=1024) + weight + bf16 cast; one block per token
__global__ __launch_bounds__(256) void rmsnorm_cast_k(
    const float* __restrict__ x, const float* __restrict__ w,
    unsigned short* __restrict__ out)
{
  __shared__ float red[4];
  const int row = blockIdx.x, t = threadIdx.x;
  const float4 v = reinterpret_cast<const float4*>(x + (long long)row * HID_)[t];
  float ss = v.x * v.x + v.y * v.y + v.z * v.z + v.w * v.w;
  #pragma unroll
  for (int off = 32; off > 0; off >>= 1) ss += __shfl_down(ss, off, 64);
  if ((t & 63) == 0) red[t >> 6] = ss;
  __syncthreads();
  ss = red[0] + red[1] + red[2] + red[3];
  const float inv = rsqrtf(ss * (1.0f / HID_) + 1e-6f);
  const float4 wv = reinterpret_cast<const float4*>(w)[t];
  ushort4 o;
  o.x = f32_to_bf16(v.x * inv * wv.x);
  o.y = f32_to_bf16(v.y * inv * wv.y);
  o.z = f32_to_bf16(v.z * inv * wv.z);
  o.w = f32_to_bf16(v.w * inv * wv.w);
  reinterpret_cast<ushort4*>(out + (long long)row * HID_)[t] = o;
}

// softmax over a 2048-wide fp32 row; writes P bf16 IN PLACE over the row
__global__ __launch_bounds__(256) void softmax_rows_k(float* __restrict__ scores)
{
  __shared__ float red[4];
  const long long rbase = ((long long)blockIdx.y * S_ + blockIdx.x) * S_;
  float* row = scores + rbase;
  const int t = threadIdx.x;
  float v[8];
  #pragma unroll
  for (int i = 0; i < 8; ++i) v[i] = row[t + i * 256];
  float m = v[0];
  #pragma unroll
  for (int i = 1; i < 8; ++i) m = fmaxf(m, v[i]);
  #pragma unroll
  for (int off = 32; off > 0; off >>= 1) m = fmaxf(m, __shfl_down(m, off, 64));
  if ((t & 63) == 0) red[t >> 6] = m;
  __syncthreads();
  m = fmaxf(fmaxf(red[0], red[1]), fmaxf(red[2], red[3]));
  __syncthreads();
  float s = 0.f;
  #pragma unroll
  for (int i = 0; i < 8; ++i) { v[i] = __expf(v[i] - m); s += v[i]; }
  #pragma unroll
  for (int off = 32; off > 0; off >>= 1) s += __shfl_down(s, off, 64);
  if ((t & 63) == 0) red[t >> 6] = s;
  __syncthreads();
  const float inv = 1.0f / (red[0] + red[1] + red[2] + red[3]);
  unsigned short* prow = reinterpret_cast<unsigned short*>(scores) + rbase * 2;
  #pragma unroll
  for (int i = 0; i < 8; ++i) prow[t + i * 256] = f32_to_bf16(v[i] * inv);
}

// router: fp32 rms(h1)*ln2w @ router_w + b, softmax over E=4. One wave/token.
__global__ __launch_bounds__(256) void router_k(
    const float* __restrict__ h1, const float* __restrict__ ln2w,
    const float* __restrict__ rwgt, const float* __restrict__ rbias,
    float* __restrict__ rw)
{
  const int wv = threadIdx.x >> 6, lane = threadIdx.x & 63;
  const long long m = (long long)blockIdx.x * 4 + wv;
  const float* xr = h1 + m * HID_;
  float xv[16];
  float ss = 0.f;
  #pragma unroll
  for (int i = 0; i < 16; ++i) { xv[i] = xr[lane + i * 64]; ss += xv[i] * xv[i]; }
  #pragma unroll
  for (int off = 32; off > 0; off >>= 1) ss += __shfl_down(ss, off, 64);
  ss = __shfl(ss, 0, 64);
  const float inv = rsqrtf(ss * (1.0f / HID_) + 1e-6f);
  float l0 = 0, l1 = 0, l2 = 0, l3 = 0;
  #pragma unroll
  for (int i = 0; i < 16; ++i) {
    const int k = lane + i * 64;
    const float xn = xv[i] * inv * ln2w[k];
    const float4 wr = reinterpret_cast<const float4*>(rwgt)[k];
    l0 += xn * wr.x; l1 += xn * wr.y; l2 += xn * wr.z; l3 += xn * wr.w;
  }
  #pragma unroll
  for (int off = 32; off > 0; off >>= 1) {
    l0 += __shfl_down(l0, off, 64);
    l1 += __shfl_down(l1, off, 64);
    l2 += __shfl_down(l2, off, 64);
    l3 += __shfl_down(l3, off, 64);
  }
  if (lane == 0) {
    l0 += rbias[0]; l1 += rbias[1]; l2 += rbias[2]; l3 += rbias[3];
    const float mx = fmaxf(fmaxf(l0, l1), fmaxf(l2, l3));
    const float e0 = __expf(l0 - mx), e1 = __expf(l1 - mx);
    const float e2 = __expf(l2 - mx), e3 = __expf(l3 - mx);
    const float is = 1.0f / (e0 + e1 + e2 + e3);
    reinterpret_cast<float4*>(rw)[m] = make_float4(e0 * is, e1 * is, e2 * is, e3 * is);
  }
}

// balance loss: single block, deterministic
__global__ __launch_bounds__(256) void balance_k(const float* __restrict__ rw,
                                                 float* __restrict__ out_scalar)
{
  __shared__ float red[4];
  float acc = 0.f;
  for (int it = threadIdx.x; it < S_ * E_; it += 256) {
    const int s = it >> 2, e = it & 3;
    float mr = 0.f;
    #pragma unroll
    for (int b = 0; b < B_; ++b) mr += rw[((long long)b * S_ + s) * E_ + e];
    mr *= (1.0f / B_);
    const float d = mr - 1.0f / E_;
    acc += d * d;
  }
  #pragma unroll
  for (int off = 32; off > 0; off >>= 1) acc += __shfl_down(acc, off, 64);
  if ((threadIdx.x & 63) == 0) red[threadIdx.x >> 6] = acc;
  __syncthreads();
  if (threadIdx.x == 0)
    out_scalar[0] = (red[0] + red[1] + red[2] + red[3]) * (0.01f / (S_ * E_));
}

extern "C" void kernel_launch(void* const* d_in, const int* in_sizes, int n_in,
                              void* d_out, int out_size, void* d_ws, size_t ws_size,
                              hipStream_t stream)
{
  const float* hidden   = (const float*)d_in[0];
  const float* ln1w     = (const float*)d_in[1];
  const float* wq       = (const float*)d_in[2];
  const float* wk       = (const float*)d_in[3];
  const float* wv       = (const float*)d_in[4];
  const float* wo       = (const float*)d_in[5];
  const float* ln2w     = (const float*)d_in[6];
  const float* router_w = (const float*)d_in[7];
  const float* router_b = (const float*)d_in[8];
  const float* gate_w   = (const float*)d_in[9];
  const float* up_w     = (const float*)d_in[10];
  const float* down_w   = (const float*)d_in[11];
  float* out = (float*)d_out;   // h1 lives here; MoE accumulates in place

  char* ws = (char*)d_ws;
  size_t off = 0;
  auto carve = [&](size_t bytes) {
    off = (off + 255) & ~(size_t)255;
    char* p = ws + off;
    off += bytes;
    return p;
  };
  unsigned short* wqT   = (unsigned short*)carve((size_t)HID_ * HID_ * 2);  // 2 MiB
  unsigned short* wkT   = (unsigned short*)carve((size_t)HID_ * HID_ * 2);
  unsigned short* wvT   = (unsigned short*)carve((size_t)HID_ * HID_ * 2);
  unsigned short* woT   = (unsigned short*)carve((size_t)HID_ * HID_ * 2);
  unsigned short* x_bf  = (unsigned short*)carve((size_t)M_ * HID_ * 2);    // 16 MiB, reused as o_bf
  unsigned short* qb    = (unsigned short*)carve((size_t)M_ * HID_ * 2);    // 16 MiB, reused as x2_bf
  unsigned short* kb    = (unsigned short*)carve((size_t)M_ * HID_ * 2);    // 16 MiB \ gu0 (32 MiB)
  unsigned short* vT    = (unsigned short*)carve((size_t)M_ * HID_ * 2);    // 16 MiB /
  float*          rwbuf = (float*)carve((size_t)M_ * E_ * 4);               // 128 KiB
  char*           ubase = carve((size_t)NHG_ * S_ * S_ * 4);                // 64 MiB union
  float*          scores = (float*)ubase;
  unsigned short* gateT = (unsigned short*)(ubase);                          // 16 MiB
  unsigned short* upT   = (unsigned short*)(ubase + (size_t)16 * 1024 * 1024);
  unsigned short* downT = (unsigned short*)(ubase + (size_t)32 * 1024 * 1024);
  unsigned short* o_bf  = x_bf;
  unsigned short* x2_bf = qb;
  unsigned short* gu0   = kb;   // spans kb+vT = 32 MiB
  // second 32 MiB buffer: u staging / gu of the odd expert
  unsigned short* gu1   = (unsigned short*)carve((size_t)M_ * IM_ * 2);     // +32 MiB
  const bool paired = (ws_size >= off);

  const dim3 blk256(256), blkT(32, 8);

  // 1) attention weights -> bf16 B^T (one dispatch, z=4)
  transpose_cast4_k<<<dim3(32, 32, 4), blkT, 0, stream>>>(wq, wk, wv, wo, wqT, HID_, HID_);

  // 2) x = bf16(rms(hidden, ln1_w))
  rmsnorm_cast_k<<<M_, blk256, 0, stream>>>(hidden, ln1w, x_bf);

  // 3) Q+K fused (dual-B, shared A staging, elu+1 epilogue); V transposed
  gemm_dual_k<EPI2_QK><<<dim3(8, 64, 1), blk256, 0, stream>>>(
      x_bf, wqT, wkT, 0, qb, kb, nullptr);
  {
    EpiAux a{}; a.c_bf16 = vT;
    gemm_bf16k<EPI_VT><<<dim3(8, 64, 1), blk256, 0, stream>>>(
        x_bf, HID_, 0, 0, 0, wvT, HID_, 0, 0, 0, 0, 0, 0, HID_, a);
  }

  // 4) attention, NHG_=4 heads per group; scores slab reused per group
  for (int grp = 0; grp < 16 / NHG_; ++grp) {
    EpiAux as{}; as.c_f32 = scores; as.ldc = S_; as.strideCz = (long long)S_ * S_;
    gemm_bf16k<EPI_F32><<<dim3(16, 16, NHG_), blk256, 0, stream>>>(
        qb, HID_, (long long)S_ * HID_, HD_, grp * NHG_,
        kb, HID_, (long long)S_ * HID_, HD_, grp * NHG_,
        2, 3, 0, HD_, as);
    softmax_rows_k<<<dim3(S_, NHG_, 1), blk256, 0, stream>>>(scores);
    EpiAux ap{}; ap.c_bf16 = o_bf;
    gemm_bf16k<EPI_PV_O><<<dim3(2, 16, NHG_), blk256, 0, stream>>>(
        (const unsigned short*)scores, 2 * S_, (long long)S_ * 2 * S_, 0, 0,
        vT, S_, (long long)HD_ * S_, 0, grp * NHG_,
        0, 0, grp * NHG_, S_, ap);
  }

  // 5) MoE weights -> bf16 B^T into the now-dead scores slab
  transpose_cast2x4_k<<<dim3(64, 32, 8), blkT, 0, stream>>>(
      gate_w, up_w, gateT, upT, HID_, IM_);
  transpose_cast_k<<<dim3(32, 64, E_), blkT, 0, stream>>>(down_w, downT, IM_, HID_);

  // 6) h1 = hidden + O @ wo, written straight into d_out
  {
    EpiAux a{}; a.add_src = hidden; a.out2 = out;
    gemm_bf16k<EPI_WO><<<dim3(8, 64, 1), blk256, 0, stream>>>(
        o_bf, HID_, 0, 0, 0, woT, HID_, 0, 0, 0, 0, 0, 0, HID_, a);
  }

  // 7) x2 = bf16(rms(h1, ln2_w)); router (fp32); balance loss scalar
  rmsnorm_cast_k<<<M_, blk256, 0, stream>>>(out, ln2w, x2_bf);
  router_k<<<M_ / 4, blk256, 0, stream>>>(out, ln2w, router_w, router_b, rwbuf);
  balance_k<<<1, blk256, 0, stream>>>(rwbuf, out + (size_t)M_ * HID_);

  // 8) dense MoE on the 8-phase 256-class GEMM.
  //    Per expert pair: up(e0)->Q, gate(e0) fuses silu*u*rw -> P,
  //    up(e1)->Q, gate(e1) in-place on Q (elementwise 1:1, race-free),
  //    down pair: out += P @ dT0^T + Q @ dT1^T (K-concat, BM=128 tile).
  const size_t wsz = (size_t)IM_ * HID_;
  if (paired) {
    const dim3 g8(IM_ / 256, M_ / 256), gd(HID_ / 256, M_ / 128), b512(512);
    unsigned short* P = gu0;
    unsigned short* Q = gu1;
    for (int p = 0; p < 2; ++p) {
      const int e0 = 2 * p, e1 = e0 + 1;
      gemm8p_k<256, EPI8_U, HID_, HID_, false><<<g8, b512, 0, stream>>>(
          x2_bf, nullptr, upT + (size_t)e0 * wsz, nullptr,
          nullptr, nullptr, 0, Q, nullptr, IM_);
      gemm8p_k<256, EPI8_GATE, HID_, HID_, false><<<g8, b512, 0, stream>>>(
          x2_bf, nullptr, gateT + (size_t)e0 * wsz, nullptr,
          Q, rwbuf, e0, P, nullptr, IM_);
      gemm8p_k<256, EPI8_U, HID_, HID_, false><<<g8, b512, 0, stream>>>(
          x2_bf, nullptr, upT + (size_t)e1 * wsz, nullptr,
          nullptr, nullptr, 0, Q, nullptr, IM_);
      gemm8p_k<256, EPI8_GATE, HID_, HID_, false><<<g8, b512, 0, stream>>>(
          x2_bf, nullptr, gateT + (size_t)e1 * wsz, nullptr,
          Q, rwbuf, e1, Q, nullptr, IM_);
      gemm8p_k<128, EPI8_DOWN, 2 * IM_, IM_, true><<<gd, b512, 0, stream>>>(
          P, Q, downT + (size_t)e0 * wsz, downT + (size_t)e1 * wsz,
          nullptr, nullptr, 0, nullptr, out, HID_);
    }
  } else {
    for (int i = 0; i < E_; ++i) {
      gemm_dual_k<EPI2_GU><<<dim3(16, 64, 1), blk256, 0, stream>>>(
          x2_bf, gateT + (size_t)i * wsz, upT + (size_t)i * wsz, i, gu0, nullptr, rwbuf);
      EpiAux ad{}; ad.out2 = out;
      gemm_bf16k<EPI_DOWN><<<dim3(8, 64, 1), blk256, 0, stream>>>(
          gu0, IM_, 0, 0, 0, downT + (size_t)i * wsz, IM_, 0, 0, 0,
          0, 0, 0, IM_, ad);
    }
  }
}

// Round 2
// 1069.800 us; speedup vs baseline: 1.1137x; 1.1137x over previous
//
#include <hip/hip_runtime.h>
#include <cstdint>
#include <cstddef>

// Problem constants (B,S,HID,NH,IM,E fixed by the reference)
#define B_    4
#define S_    2048
#define HID_  1024
#define NH_   4
#define HD_   256     // HID/NH
#define IM_   2048
#define E_    4
#define M_    8192    // B_*S_ tokens
#define NHG_  4       // heads per attention group

typedef __bf16 bf16x8 __attribute__((ext_vector_type(8)));
typedef float  f32x4  __attribute__((ext_vector_type(4)));

__device__ __forceinline__ unsigned short f32_to_bf16(float f) {
  unsigned int u = __float_as_uint(f);
  u += 0x7fffu + ((u >> 16) & 1u);   // round-to-nearest-even
  return (unsigned short)(u >> 16);
}

// async 16B global->LDS DMA (global_load_lds_dwordx4). LDS dest is
// wave-uniform base + lane*16 -> LDS layout contiguous in lane order.
__device__ __forceinline__ void gload16(const unsigned short* g, unsigned short* l) {
  __builtin_amdgcn_global_load_lds(
      (const __attribute__((address_space(1))) void*)g,
      (__attribute__((address_space(3))) void*)l, 16, 0, 0);
}

// XCD-aware swizzle: contiguous y-bands per XCD.
__device__ __forceinline__ void swizzle_xy(int& bx, int& by) {
  const int gx = gridDim.x, gy = gridDim.y;
  const int flat = blockIdx.x + blockIdx.y * gx;
  const int xcd = flat & 7, i = flat >> 3;
  const int rpx = gy >> 3;          // y-rows per XCD
  bx = i % gx;
  by = xcd * rpx + i / gx;
}

// ---------------- epilogue variants (generic single-B GEMM) ----------------
#define EPI_F32      0   // C fp32 (attention scores), batched via strideCz
#define EPI_VT       2   // write V^T [b][h][d][s] bf16
#define EPI_PV_O     3   // write attn O into [token][h*HD+n] bf16
#define EPI_WO       4   // out2 = add_src + acc  (h1 into d_out)
#define EPI_DOWN     5   // out2 += acc  (fallback path)

struct EpiAux {
  float* c_f32;
  unsigned short* c_bf16;
  const float* add_src;       // hidden (WO)
  float* out2;                // d_out (WO/DOWN)
  long long strideCz;
  int ldc;
};

// Generic batched GEMM: C[z] = A[z] (MxK, row-major, lda) @ B[z]^T.
// 128x128 tile, BK=32, 4 waves x (4x4) 16x16x32 bf16 MFMA fragments.
// Double-buffered LDS, one-iteration-ahead async global_load_lds prefetch.
// 32 KiB LDS + ~152 regs -> ~3 blocks/CU (m97-grade overlap).
template<int EPI>
__global__ __launch_bounds__(256) void gemm_bf16k(
    const unsigned short* __restrict__ A, int lda, long long sAo, long long sAi, int zbA,
    const unsigned short* __restrict__ B, int ldb, long long sBo, long long sBi, int zbB,
    int zshift, int zmask, int zbC, int K, EpiAux aux)
{
  __shared__ unsigned short As[2][128 * 32];
  __shared__ unsigned short Bs[2][128 * 32];

  const int t = threadIdx.x;
  int bx, by;
  swizzle_xy(bx, by);
  const int m0 = by * 128, n0 = bx * 128;
  const int z  = blockIdx.z;
  const int zA = z + zbA, zB = z + zbB, zC = z + zbC;
  const unsigned short* Ab = A + (long long)(zA >> zshift) * sAo + (long long)(zA & zmask) * sAi;
  const unsigned short* Bb = B + (long long)(zB >> zshift) * sBo + (long long)(zB & zmask) * sBi;

  const int lane = t & 63, wave = t >> 6;
  const int wm = (wave >> 1) * 64, wn = (wave & 1) * 64;
  const int lrow = lane & 15, quad = lane >> 4;

  f32x4 acc[4][4] = {};

  const int srow = lane >> 2;         // 0..15
  const int sko  = (lane & 3) * 8;    // k-elem 0/8/16/24
  const unsigned short* aRow0 = Ab + (long long)(m0 + wave * 16       + srow) * lda + sko;
  const unsigned short* aRow1 = Ab + (long long)(m0 + (wave + 4) * 16 + srow) * lda + sko;
  const unsigned short* bRow0 = Bb + (long long)(n0 + wave * 16       + srow) * ldb + sko;
  const unsigned short* bRow1 = Bb + (long long)(n0 + (wave + 4) * 16 + srow) * ldb + sko;
  const int dst0 = (wave * 16) * 32, dst1 = ((wave + 4) * 16) * 32;

  gload16(aRow0, &As[0][dst0]);
  gload16(aRow1, &As[0][dst1]);
  gload16(bRow0, &Bs[0][dst0]);
  gload16(bRow1, &Bs[0][dst1]);

  int cur = 0;
  for (int kk = 0; kk < K; kk += 32, cur ^= 1) {
    __syncthreads();
    if (kk + 32 < K) {
      const int nxt = cur ^ 1, k2 = kk + 32;
      gload16(aRow0 + k2, &As[nxt][dst0]);
      gload16(aRow1 + k2, &As[nxt][dst1]);
      gload16(bRow0 + k2, &Bs[nxt][dst0]);
      gload16(bRow1 + k2, &Bs[nxt][dst1]);
    }
    bf16x8 af[4], bfr[4];
    #pragma unroll
    for (int i = 0; i < 4; ++i) {
      af[i]  = *reinterpret_cast<const bf16x8*>(&As[cur][(wm + i * 16 + lrow) * 32 + quad * 8]);
      bfr[i] = *reinterpret_cast<const bf16x8*>(&Bs[cur][(wn + i * 16 + lrow) * 32 + quad * 8]);
    }
    #pragma unroll
    for (int i = 0; i < 4; ++i)
      #pragma unroll
      for (int j = 0; j < 4; ++j)
        acc[i][j] = __builtin_amdgcn_mfma_f32_16x16x32_bf16(af[i], bfr[j], acc[i][j], 0, 0, 0);
  }

  // epilogue: D row = quad*4+r, col = lane&15
  #pragma unroll
  for (int mi = 0; mi < 4; ++mi) {
    #pragma unroll
    for (int ni = 0; ni < 4; ++ni) {
      #pragma unroll
      for (int r = 0; r < 4; ++r) {
        const int gm = m0 + wm + mi * 16 + quad * 4 + r;
        const int gn = n0 + wn + ni * 16 + lrow;
        const float val = acc[mi][ni][r];
        if (EPI == EPI_F32) {
          aux.c_f32[(long long)zC * aux.strideCz + (long long)gm * aux.ldc + gn] = val;
        } else if (EPI == EPI_VT) {
          const int b = gm >> 11, s = gm & (S_ - 1);
          const int h = gn >> 8, d = gn & (HD_ - 1);
          aux.c_bf16[((long long)(b * NH_ + h) * HD_ + d) * S_ + s] = f32_to_bf16(val);
        } else if (EPI == EPI_PV_O) {
          const int b = zC >> 2, h = zC & (NH_ - 1);
          aux.c_bf16[((long long)(b * S_ + gm)) * HID_ + h * HD_ + gn] = f32_to_bf16(val);
        } else if (EPI == EPI_WO) {
          const long long idx = (long long)gm * HID_ + gn;
          aux.out2[idx] = val + aux.add_src[idx];
        } else if (EPI == EPI_DOWN) {
          const long long idx = (long long)gm * HID_ + gn;
          aux.out2[idx] += val;
        }
      }
    }
  }
}

// ---- old dual-B GEMM, kept ONLY for the small-workspace fallback path ----
#define EPI2_GU 1   // out0 = bf16(silu(g)*u*rw[token][zb]), ldc=IM_

template<int EPI2>
__global__ __launch_bounds__(256, 2) void gemm_dual_k(
    const unsigned short* __restrict__ A,      // [M_][HID_]
    const unsigned short* __restrict__ B0b,    // B0 [*][HID_]
    const unsigned short* __restrict__ B1b,    // B1 [*][HID_]
    int zb,
    unsigned short* __restrict__ out0, unsigned short* __restrict__ out1,
    const float* __restrict__ rw)
{
  __shared__ unsigned short As[2][128 * 32];
  __shared__ unsigned short B0s[2][128 * 32];
  __shared__ unsigned short B1s[2][128 * 32];

  const int t = threadIdx.x;
  int bx, by;
  swizzle_xy(bx, by);
  const int m0 = by * 128, n0 = bx * 128;

  const int lane = t & 63, wave = t >> 6;
  const int wm = (wave >> 1) * 64, wn = (wave & 1) * 64;
  const int lrow = lane & 15, quad = lane >> 4;

  f32x4 acc0[4][4] = {}, acc1[4][4] = {};

  const int srow = lane >> 2;
  const int sko  = (lane & 3) * 8;
  const unsigned short* aRow0 = A   + (long long)(m0 + wave * 16       + srow) * HID_ + sko;
  const unsigned short* aRow1 = A   + (long long)(m0 + (wave + 4) * 16 + srow) * HID_ + sko;
  const unsigned short* gRow0 = B0b + (long long)(n0 + wave * 16       + srow) * HID_ + sko;
  const unsigned short* gRow1 = B0b + (long long)(n0 + (wave + 4) * 16 + srow) * HID_ + sko;
  const unsigned short* uRow0 = B1b + (long long)(n0 + wave * 16       + srow) * HID_ + sko;
  const unsigned short* uRow1 = B1b + (long long)(n0 + (wave + 4) * 16 + srow) * HID_ + sko;
  const int dst0 = (wave * 16) * 32, dst1 = ((wave + 4) * 16) * 32;

  gload16(aRow0, &As[0][dst0]);
  gload16(aRow1, &As[0][dst1]);
  gload16(gRow0, &B0s[0][dst0]);
  gload16(gRow1, &B0s[0][dst1]);
  gload16(uRow0, &B1s[0][dst0]);
  gload16(uRow1, &B1s[0][dst1]);

  int cur = 0;
  for (int kk = 0; kk < HID_; kk += 32, cur ^= 1) {
    __syncthreads();
    if (kk + 32 < HID_) {
      const int nxt = cur ^ 1, k2 = kk + 32;
      gload16(aRow0 + k2, &As[nxt][dst0]);
      gload16(aRow1 + k2, &As[nxt][dst1]);
      gload16(gRow0 + k2, &B0s[nxt][dst0]);
      gload16(gRow1 + k2, &B0s[nxt][dst1]);
      gload16(uRow0 + k2, &B1s[nxt][dst0]);
      gload16(uRow1 + k2, &B1s[nxt][dst1]);
    }
    bf16x8 af[4], b0[4], b1[4];
    #pragma unroll
    for (int i = 0; i < 4; ++i) {
      af[i] = *reinterpret_cast<const bf16x8*>(&As[cur][(wm + i * 16 + lrow) * 32 + quad * 8]);
      b0[i] = *reinterpret_cast<const bf16x8*>(&B0s[cur][(wn + i * 16 + lrow) * 32 + quad * 8]);
      b1[i] = *reinterpret_cast<const bf16x8*>(&B1s[cur][(wn + i * 16 + lrow) * 32 + quad * 8]);
    }
    #pragma unroll
    for (int i = 0; i < 4; ++i)
      #pragma unroll
      for (int j = 0; j < 4; ++j) {
        acc0[i][j] = __builtin_amdgcn_mfma_f32_16x16x32_bf16(af[i], b0[j], acc0[i][j], 0, 0, 0);
        acc1[i][j] = __builtin_amdgcn_mfma_f32_16x16x32_bf16(af[i], b1[j], acc1[i][j], 0, 0, 0);
      }
  }

  #pragma unroll
  for (int mi = 0; mi < 4; ++mi)
    #pragma unroll
    for (int r = 0; r < 4; ++r) {
      const int gm = m0 + wm + mi * 16 + quad * 4 + r;
      const float rwv = rw[(long long)gm * E_ + zb];
      #pragma unroll
      for (int ni = 0; ni < 4; ++ni) {
        const int gn = n0 + wn + ni * 16 + lrow;
        const float v0 = acc0[mi][ni][r];
        const float v1 = acc1[mi][ni][r];
        const float sg = v0 / (1.f + __expf(-v0));      // silu(gate)
        out0[(long long)gm * IM_ + gn] = f32_to_bf16(sg * v1 * rwv);
      }
    }
}

// =============== 4-phase pipelined GEMM, 16 MFMA per phase ==================
// BM=256 x BN=128 tile, BK=64, 512 threads = 8 waves (4M x 2N), per-wave
// 64x64 output per accumulator set. Staging unit = 128 rows x 64 k (16 KiB,
// 2 x gload16/thread); LDS XOR-swizzle via pre-swizzled global source +
// swizzled ds_read (byte-validated in round 1: SQ_LDS_BANK_CONFLICT == 0).
//
// DUAL (shared-A, two B mats, acc0/acc1): 4 phases per K-tile, phase (s,k):
//   ph0: readA[k0](4)+readB0[k0](4); stage B0(T+1)->c^1; BAR; lgk0; 16 MFMA acc0
//   ph1: readB1[k0](4);              stage B1(T+1)->c^1; BAR; lgk0; 16 MFMA acc1
//   ph2: readA[k1](4)+readB0[k1](4);                     BAR; lgk0; 16 MFMA acc0
//   ph3: readB1[k1](4); stage A(T+2)->c; vmcnt(4);       BAR; lgk0; 16 MFMA acc1
// SINGLE (+PAIRK expert-concat over K): 2 phases per K-tile:
//   ph0: readA[k0]+readA[k1]+readB[k0]; stage B(T+1)->c^1; BAR; lgk0; 16 MFMA
//   ph1: readB[k1]; stage A(T+2)->c; vmcnt(4);             BAR; lgk0; 16 MFMA
// Counted vmcnt(4) once per K-tile keeps A(T+2) in flight while guaranteeing
// everything tile T+1 reads has landed (before a barrier -> cross-wave safe).
// vmcnt(0) only when the pipeline tail stops staging (T+2 >= NT).
// WAR safety: every stage targets an LDS region whose last ds_reads drained
// at a previous phase's lgkmcnt(0) + closing barrier.
#define EPI4_GU   0   // out0 = bf16(silu(acc0)*acc1*rw[token][expert]), ld IM_
#define EPI4_QK   1   // out0/out1 = bf16(elu(acc)+1), ld HID_
#define EPI4_DOWN 2   // o_f32 += acc0, ld HID_
template<bool DUAL, int EPI, int KTOT, int KROW, bool PAIRK>
__global__ __launch_bounds__(512, 2) void gemm4p_k(
    const unsigned short* A0, const unsigned short* A1,
    const unsigned short* B0b, const unsigned short* B1b,
    const float* __restrict__ rw, int expert,
    unsigned short* out0, unsigned short* out1, float* o_f32)
{
  constexpr int NT  = KTOT / 64;
  constexpr int NT2 = NT / 2;
  // elems: A 2buf x (2 units x 8192); B0 @32768, 2buf x 8192; B1 @49152
  __shared__ unsigned short smem[DUAL ? 65536 : 49152];

  const int t = threadIdx.x, wave = t >> 6, lane = t & 63;
  const int lrow = lane & 15, quad = lane >> 4;
  const int wrow0 = (wave >> 1) * 64;   // 0..192
  const int wcol0 = (wave & 1) * 64;    // 0/64

  int bx, by;
  swizzle_xy(bx, by);
  const int m0 = by * 256, n0 = bx * 128;

  const int r8  = lane >> 3;
  const int csw = ((lane & 7) ^ r8) << 4;   // pre-swizzled global byte col

  auto stage_unit = [&](const unsigned short* mat, int grow0, int ktl, int ldsElem) {
    #pragma unroll
    for (int i = 0; i < 2; ++i) {
      const char* src = (const char*)(mat + (size_t)(grow0 + wave * 16 + i * 8 + r8) * KROW)
                        + (size_t)ktl * 128 + csw;
      gload16((const unsigned short*)src, &smem[ldsElem + wave * 1024 + i * 512]);
    }
  };
  auto stageA = [&](int kt, int buf) {
    const unsigned short* m = A0; int ktl = kt;
    if (PAIRK && kt >= NT2) { m = A1; ktl = kt - NT2; }
    stage_unit(m, m0,       ktl, buf * 16384);
    stage_unit(m, m0 + 128, ktl, buf * 16384 + 8192);
  };
  auto stageB = [&](int kt, int buf, int which) {
    const unsigned short* m; int ktl = kt; int base;
    if (PAIRK) {
      if (kt >= NT2) { m = B1b; ktl = kt - NT2; } else { m = B0b; }
      base = 32768;
    } else {
      m = which ? B1b : B0b;
      base = which ? 49152 : 32768;
    }
    stage_unit(m, n0, ktl, base + buf * 8192);
  };

  const int xr = (lane & 7) << 4;
  auto readA_ = [&](bf16x8* o, int buf, int ks) {
    const char* base = (const char*)smem + buf * 32768 + (wrow0 >> 7) * 16384;
    const int rl0 = wrow0 & 64;
    #pragma unroll
    for (int mi = 0; mi < 4; ++mi)
      o[mi] = *(const bf16x8*)(base + (rl0 + mi * 16 + lrow) * 128 + ((ks * 64 + quad * 16) ^ xr));
  };
  auto readB_ = [&](bf16x8* o, int buf, int which, int ks) {
    const char* base = (const char*)smem + (which ? 98304 : 65536) + buf * 16384;
    #pragma unroll
    for (int nj = 0; nj < 4; ++nj)
      o[nj] = *(const bf16x8*)(base + (wcol0 + nj * 16 + lrow) * 128 + ((ks * 64 + quad * 16) ^ xr));
  };

  f32x4 acc0[4][4] = {};
  f32x4 acc1[4][4] = {};
  auto mm = [&](f32x4 (&ac)[4][4], const bf16x8* aF, const bf16x8* bF) {
    #pragma unroll
    for (int mi = 0; mi < 4; ++mi)
      #pragma unroll
      for (int nj = 0; nj < 4; ++nj)
        ac[mi][nj] = __builtin_amdgcn_mfma_f32_16x16x32_bf16(aF[mi], bF[nj], ac[mi][nj], 0, 0, 0);
  };

  // prologue: T0 complete + T1's A; counted wait leaves A(1) in flight
  stageA(0, 0);
  stageB(0, 0, 0);
  if (DUAL) stageB(0, 0, 1);
  stageA(1, 1);
  asm volatile("s_waitcnt vmcnt(4)" ::: "memory");
  __builtin_amdgcn_s_barrier();

  bf16x8 a0[4], a1[4], bF[4];
  for (int T = 0; T < NT; ++T) {
    const int c = T & 1;
    if (DUAL) {
      // ph0
      readA_(a0, c, 0); readB_(bF, c, 0, 0);
      if (T + 1 < NT) stageB(T + 1, c ^ 1, 0);
      __builtin_amdgcn_s_barrier();
      asm volatile("s_waitcnt lgkmcnt(0)" ::: "memory");
      __builtin_amdgcn_s_setprio(1); mm(acc0, a0, bF); __builtin_amdgcn_s_setprio(0);
      __builtin_amdgcn_s_barrier();
      // ph1
      readB_(bF, c, 1, 0);
      if (T + 1 < NT) stageB(T + 1, c ^ 1, 1);
      __builtin_amdgcn_s_barrier();
      asm volatile("s_waitcnt lgkmcnt(0)" ::: "memory");
      __builtin_amdgcn_s_setprio(1); mm(acc1, a0, bF); __builtin_amdgcn_s_setprio(0);
      __builtin_amdgcn_s_barrier();
      // ph2
      readA_(a1, c, 1); readB_(bF, c, 0, 1);
      __builtin_amdgcn_s_barrier();
      asm volatile("s_waitcnt lgkmcnt(0)" ::: "memory");
      __builtin_amdgcn_s_setprio(1); mm(acc0, a1, bF); __builtin_amdgcn_s_setprio(0);
      __builtin_amdgcn_s_barrier();
      // ph3
      readB_(bF, c, 1, 1);
      if (T + 2 < NT) { stageA(T + 2, c); asm volatile("s_waitcnt vmcnt(4)" ::: "memory"); }
      else            { asm volatile("s_waitcnt vmcnt(0)" ::: "memory"); }
      __builtin_amdgcn_s_barrier();
      asm volatile("s_waitcnt lgkmcnt(0)" ::: "memory");
      __builtin_amdgcn_s_setprio(1); mm(acc1, a1, bF); __builtin_amdgcn_s_setprio(0);
      __builtin_amdgcn_s_barrier();
    } else {
      // ph0 (a1 read early so ph1's A-stage is WAR-safe across waves)
      readA_(a0, c, 0); readA_(a1, c, 1); readB_(bF, c, 0, 0);
      if (T + 1 < NT) stageB(T + 1, c ^ 1, 0);
      __builtin_amdgcn_s_barrier();
      asm volatile("s_waitcnt lgkmcnt(0)" ::: "memory");
      __builtin_amdgcn_s_setprio(1); mm(acc0, a0, bF); __builtin_amdgcn_s_setprio(0);
      __builtin_amdgcn_s_barrier();
      // ph1
      readB_(bF, c, 0, 1);
      if (T + 2 < NT) { stageA(T + 2, c); asm volatile("s_waitcnt vmcnt(4)" ::: "memory"); }
      else            { asm volatile("s_waitcnt vmcnt(0)" ::: "memory"); }
      __builtin_amdgcn_s_barrier();
      asm volatile("s_waitcnt lgkmcnt(0)" ::: "memory");
      __builtin_amdgcn_s_setprio(1); mm(acc0, a1, bF); __builtin_amdgcn_s_setprio(0);
      __builtin_amdgcn_s_barrier();
    }
  }

  // epilogue: D row = quad*4+r, col = lane&15
  #pragma unroll
  for (int mi = 0; mi < 4; ++mi) {
    #pragma unroll
    for (int r = 0; r < 4; ++r) {
      const int gm = m0 + wrow0 + mi * 16 + quad * 4 + r;
      float rwv = 0.f;
      if (EPI == EPI4_GU) rwv = rw[(size_t)gm * E_ + expert];
      #pragma unroll
      for (int nj = 0; nj < 4; ++nj) {
        const int gn = n0 + wcol0 + nj * 16 + lrow;
        const float v0 = acc0[mi][nj][r];
        if (EPI == EPI4_GU) {
          const float v1 = acc1[mi][nj][r];
          const float sg = v0 / (1.f + __expf(-v0));
          out0[(size_t)gm * IM_ + gn] = f32_to_bf16(sg * v1 * rwv);
        } else if (EPI == EPI4_QK) {
          const float v1 = acc1[mi][nj][r];
          out0[(size_t)gm * HID_ + gn] = f32_to_bf16(v0 > 0.f ? v0 + 1.f : __expf(v0));
          out1[(size_t)gm * HID_ + gn] = f32_to_bf16(v1 > 0.f ? v1 + 1.f : __expf(v1));
        } else {  // EPI4_DOWN
          o_f32[(size_t)gm * HID_ + gn] += v0;
        }
      }
    }
  }
}

// fp32 [R][C] -> bf16 [C][R]; z selects among 4 sources, dst stride R*C
__global__ void transpose_cast4_k(const float* s0, const float* s1,
                                  const float* s2, const float* s3,
                                  unsigned short* __restrict__ out, int R, int C)
{
  __shared__ float tile[32][33];
  const int z = blockIdx.z;
  const float* in = (z == 0) ? s0 : (z == 1) ? s1 : (z == 2) ? s2 : s3;
  unsigned short* o = out + (long long)z * R * C;
  const int c0 = blockIdx.x * 32, r0 = blockIdx.y * 32;
  const int tx = threadIdx.x, ty = threadIdx.y;
  #pragma unroll
  for (int i = 0; i < 32; i += 8)
    tile[ty + i][tx] = in[(long long)(r0 + ty + i) * C + c0 + tx];
  __syncthreads();
  #pragma unroll
  for (int i = 0; i < 32; i += 8)
    o[(long long)(c0 + ty + i) * R + r0 + tx] = f32_to_bf16(tile[tx][ty + i]);
}

// fp32 [R][C] -> bf16 [C][R]; z<4: srcA/dstA expert z; z>=4: srcB/dstB
__global__ void transpose_cast2x4_k(const float* __restrict__ sA,
                                    const float* __restrict__ sB,
                                    unsigned short* __restrict__ dA,
                                    unsigned short* __restrict__ dB,
                                    int R, int C)
{
  __shared__ float tile[32][33];
  const int z = blockIdx.z;
  const long long eo = (long long)(z & 3) * R * C;
  const float* in = ((z < 4) ? sA : sB) + eo;
  unsigned short* o = ((z < 4) ? dA : dB) + eo;
  const int c0 = blockIdx.x * 32, r0 = blockIdx.y * 32;
  const int tx = threadIdx.x, ty = threadIdx.y;
  #pragma unroll
  for (int i = 0; i < 32; i += 8)
    tile[ty + i][tx] = in[(long long)(r0 + ty + i) * C + c0 + tx];
  __syncthreads();
  #pragma unroll
  for (int i = 0; i < 32; i += 8)
    o[(long long)(c0 + ty + i) * R + r0 + tx] = f32_to_bf16(tile[tx][ty + i]);
}

// fp32 [R][C] -> bf16 [C][R], batched over z (single base, stride R*C)
__global__ void transpose_cast_k(const float* __restrict__ in,
                                 unsigned short* __restrict__ out, int R, int C)
{
  __shared__ float tile[32][33];
  const long long bo = (long long)blockIdx.z * R * C;
  const int c0 = blockIdx.x * 32, r0 = blockIdx.y * 32;
  const int tx = threadIdx.x, ty = threadIdx.y;
  #pragma unroll
  for (int i = 0; i < 32; i += 8)
    tile[ty + i][tx] = in[bo + (long long)(r0 + ty + i) * C + c0 + tx];
  __syncthreads();
  #pragma unroll
  for (int i = 0; i < 32; i += 8)
    out[bo + (long long)(c0 + ty + i) * R + r0 + tx] = f32_to_bf16(tile[tx][ty + i]);
}

// rmsnorm row (HID=1024) + weight + bf16 cast; one block per token
__global__ __launch_bounds__(256) void rmsnorm_cast_k(
    const float* __restrict__ x, const float* __restrict__ w,
    unsigned short* __restrict__ out)
{
  __shared__ float red[4];
  const int row = blockIdx.x, t = threadIdx.x;
  const float4 v = reinterpret_cast<const float4*>(x + (long long)row * HID_)[t];
  float ss = v.x * v.x + v.y * v.y + v.z * v.z + v.w * v.w;
  #pragma unroll
  for (int off = 32; off > 0; off >>= 1) ss += __shfl_down(ss, off, 64);
  if ((t & 63) == 0) red[t >> 6] = ss;
  __syncthreads();
  ss = red[0] + red[1] + red[2] + red[3];
  const float inv = rsqrtf(ss * (1.0f / HID_) + 1e-6f);
  const float4 wv = reinterpret_cast<const float4*>(w)[t];
  ushort4 o;
  o.x = f32_to_bf16(v.x * inv * wv.x);
  o.y = f32_to_bf16(v.y * inv * wv.y);
  o.z = f32_to_bf16(v.z * inv * wv.z);
  o.w = f32_to_bf16(v.w * inv * wv.w);
  reinterpret_cast<ushort4*>(out + (long long)row * HID_)[t] = o;
}

// softmax over a 2048-wide fp32 row; writes P bf16 IN PLACE over the row
__global__ __launch_bounds__(256) void softmax_rows_k(float* __restrict__ scores)
{
  __shared__ float red[4];
  const long long rbase = ((long long)blockIdx.y * S_ + blockIdx.x) * S_;
  float* row = scores + rbase;
  const int t = threadIdx.x;
  float v[8];
  #pragma unroll
  for (int i = 0; i < 8; ++i) v[i] = row[t + i * 256];
  float m = v[0];
  #pragma unroll
  for (int i = 1; i < 8; ++i) m = fmaxf(m, v[i]);
  #pragma unroll
  for (int off = 32; off > 0; off >>= 1) m = fmaxf(m, __shfl_down(m, off, 64));
  if ((t & 63) == 0) red[t >> 6] = m;
  __syncthreads();
  m = fmaxf(fmaxf(red[0], red[1]), fmaxf(red[2], red[3]));
  __syncthreads();
  float s = 0.f;
  #pragma unroll
  for (int i = 0; i < 8; ++i) { v[i] = __expf(v[i] - m); s += v[i]; }
  #pragma unroll
  for (int off = 32; off > 0; off >>= 1) s += __shfl_down(s, off, 64);
  if ((t & 63) == 0) red[t >> 6] = s;
  __syncthreads();
  const float inv = 1.0f / (red[0] + red[1] + red[2] + red[3]);
  unsigned short* prow = reinterpret_cast<unsigned short*>(scores) + rbase * 2;
  #pragma unroll
  for (int i = 0; i < 8; ++i) prow[t + i * 256] = f32_to_bf16(v[i] * inv);
}

// router: fp32 rms(h1)*ln2w @ router_w + b, softmax over E=4. One wave/token.
__global__ __launch_bounds__(256) void router_k(
    const float* __restrict__ h1, const float* __restrict__ ln2w,
    const float* __restrict__ rwgt, const float* __restrict__ rbias,
    float* __restrict__ rw)
{
  const int wv = threadIdx.x >> 6, lane = threadIdx.x & 63;
  const long long m = (long long)blockIdx.x * 4 + wv;
  const float* xr = h1 + m * HID_;
  float xv[16];
  float ss = 0.f;
  #pragma unroll
  for (int i = 0; i < 16; ++i) { xv[i] = xr[lane + i * 64]; ss += xv[i] * xv[i]; }
  #pragma unroll
  for (int off = 32; off > 0; off >>= 1) ss += __shfl_down(ss, off, 64);
  ss = __shfl(ss, 0, 64);
  const float inv = rsqrtf(ss * (1.0f / HID_) + 1e-6f);
  float l0 = 0, l1 = 0, l2 = 0, l3 = 0;
  #pragma unroll
  for (int i = 0; i < 16; ++i) {
    const int k = lane + i * 64;
    const float xn = xv[i] * inv * ln2w[k];
    const float4 wr = reinterpret_cast<const float4*>(rwgt)[k];
    l0 += xn * wr.x; l1 += xn * wr.y; l2 += xn * wr.z; l3 += xn * wr.w;
  }
  #pragma unroll
  for (int off = 32; off > 0; off >>= 1) {
    l0 += __shfl_down(l0, off, 64);
    l1 += __shfl_down(l1, off, 64);
    l2 += __shfl_down(l2, off, 64);
    l3 += __shfl_down(l3, off, 64);
  }
  if (lane == 0) {
    l0 += rbias[0]; l1 += rbias[1]; l2 += rbias[2]; l3 += rbias[3];
    const float mx = fmaxf(fmaxf(l0, l1), fmaxf(l2, l3));
    const float e0 = __expf(l0 - mx), e1 = __expf(l1 - mx);
    const float e2 = __expf(l2 - mx), e3 = __expf(l3 - mx);
    const float is = 1.0f / (e0 + e1 + e2 + e3);
    reinterpret_cast<float4*>(rw)[m] = make_float4(e0 * is, e1 * is, e2 * is, e3 * is);
  }
}

// balance loss: single block, deterministic
__global__ __launch_bounds__(256) void balance_k(const float* __restrict__ rw,
                                                 float* __restrict__ out_scalar)
{
  __shared__ float red[4];
  float acc = 0.f;
  for (int it = threadIdx.x; it < S_ * E_; it += 256) {
    const int s = it >> 2, e = it & 3;
    float mr = 0.f;
    #pragma unroll
    for (int b = 0; b < B_; ++b) mr += rw[((long long)b * S_ + s) * E_ + e];
    mr *= (1.0f / B_);
    const float d = mr - 1.0f / E_;
    acc += d * d;
  }
  #pragma unroll
  for (int off = 32; off > 0; off >>= 1) acc += __shfl_down(acc, off, 64);
  if ((threadIdx.x & 63) == 0) red[threadIdx.x >> 6] = acc;
  __syncthreads();
  if (threadIdx.x == 0)
    out_scalar[0] = (red[0] + red[1] + red[2] + red[3]) * (0.01f / (S_ * E_));
}

extern "C" void kernel_launch(void* const* d_in, const int* in_sizes, int n_in,
                              void* d_out, int out_size, void* d_ws, size_t ws_size,
                              hipStream_t stream)
{
  const float* hidden   = (const float*)d_in[0];
  const float* ln1w     = (const float*)d_in[1];
  const float* wq       = (const float*)d_in[2];
  const float* wk       = (const float*)d_in[3];
  const float* wv       = (const float*)d_in[4];
  const float* wo       = (const float*)d_in[5];
  const float* ln2w     = (const float*)d_in[6];
  const float* router_w = (const float*)d_in[7];
  const float* router_b = (const float*)d_in[8];
  const float* gate_w   = (const float*)d_in[9];
  const float* up_w     = (const float*)d_in[10];
  const float* down_w   = (const float*)d_in[11];
  float* out = (float*)d_out;   // h1 lives here; MoE accumulates in place

  char* ws = (char*)d_ws;
  size_t off = 0;
  auto carve = [&](size_t bytes) {
    off = (off + 255) & ~(size_t)255;
    char* p = ws + off;
    off += bytes;
    return p;
  };
  unsigned short* wqT   = (unsigned short*)carve((size_t)HID_ * HID_ * 2);  // 2 MiB
  unsigned short* wkT   = (unsigned short*)carve((size_t)HID_ * HID_ * 2);
  unsigned short* wvT   = (unsigned short*)carve((size_t)HID_ * HID_ * 2);
  unsigned short* woT   = (unsigned short*)carve((size_t)HID_ * HID_ * 2);
  unsigned short* x_bf  = (unsigned short*)carve((size_t)M_ * HID_ * 2);    // 16 MiB, reused as o_bf
  unsigned short* qb    = (unsigned short*)carve((size_t)M_ * HID_ * 2);    // 16 MiB, reused as x2_bf
  unsigned short* kb    = (unsigned short*)carve((size_t)M_ * HID_ * 2);    // 16 MiB \ gu0 (32 MiB)
  unsigned short* vT    = (unsigned short*)carve((size_t)M_ * HID_ * 2);    // 16 MiB /
  float*          rwbuf = (float*)carve((size_t)M_ * E_ * 4);               // 128 KiB
  char*           ubase = carve((size_t)NHG_ * S_ * S_ * 4);                // 64 MiB union
  float*          scores = (float*)ubase;
  unsigned short* gateT = (unsigned short*)(ubase);                          // 16 MiB
  unsigned short* upT   = (unsigned short*)(ubase + (size_t)16 * 1024 * 1024);
  unsigned short* downT = (unsigned short*)(ubase + (size_t)32 * 1024 * 1024);
  unsigned short* o_bf  = x_bf;
  unsigned short* x2_bf = qb;
  unsigned short* gu0   = kb;   // spans kb+vT = 32 MiB
  // second 32 MiB buffer: gu of the odd expert (down pair reads both)
  unsigned short* gu1   = (unsigned short*)carve((size_t)M_ * IM_ * 2);     // +32 MiB
  const bool paired = (ws_size >= off);

  const dim3 blk256(256), blk512(512), blkT(32, 8);

  // 1) attention weights -> bf16 B^T (one dispatch, z=4)
  transpose_cast4_k<<<dim3(32, 32, 4), blkT, 0, stream>>>(wq, wk, wv, wo, wqT, HID_, HID_);

  // 2) x = bf16(rms(hidden, ln1_w))
  rmsnorm_cast_k<<<M_, blk256, 0, stream>>>(hidden, ln1w, x_bf);

  // 3) Q+K fused (dual 4-phase, shared A staging, elu+1 epilogue); V transposed
  gemm4p_k<true, EPI4_QK, 1024, 1024, false><<<dim3(8, 32, 1), blk512, 0, stream>>>(
      x_bf, nullptr, wqT, wkT, nullptr, 0, qb, kb, nullptr);
  {
    EpiAux a{}; a.c_bf16 = vT;
    gemm_bf16k<EPI_VT><<<dim3(8, 64, 1), blk256, 0, stream>>>(
        x_bf, HID_, 0, 0, 0, wvT, HID_, 0, 0, 0, 0, 0, 0, HID_, a);
  }

  // 4) attention, NHG_=4 heads per group; scores slab reused per group
  for (int grp = 0; grp < 16 / NHG_; ++grp) {
    EpiAux as{}; as.c_f32 = scores; as.ldc = S_; as.strideCz = (long long)S_ * S_;
    gemm_bf16k<EPI_F32><<<dim3(16, 16, NHG_), blk256, 0, stream>>>(
        qb, HID_, (long long)S_ * HID_, HD_, grp * NHG_,
        kb, HID_, (long long)S_ * HID_, HD_, grp * NHG_,
        2, 3, 0, HD_, as);
    softmax_rows_k<<<dim3(S_, NHG_, 1), blk256, 0, stream>>>(scores);
    EpiAux ap{}; ap.c_bf16 = o_bf;
    gemm_bf16k<EPI_PV_O><<<dim3(2, 16, NHG_), blk256, 0, stream>>>(
        (const unsigned short*)scores, 2 * S_, (long long)S_ * 2 * S_, 0, 0,
        vT, S_, (long long)HD_ * S_, 0, grp * NHG_,
        0, 0, grp * NHG_, S_, ap);
  }

  // 5) MoE weights -> bf16 B^T into the now-dead scores slab
  transpose_cast2x4_k<<<dim3(64, 32, 8), blkT, 0, stream>>>(
      gate_w, up_w, gateT, upT, HID_, IM_);
  transpose_cast_k<<<dim3(32, 64, E_), blkT, 0, stream>>>(down_w, downT, IM_, HID_);

  // 6) h1 = hidden + O @ wo, written straight into d_out
  {
    EpiAux a{}; a.add_src = hidden; a.out2 = out;
    gemm_bf16k<EPI_WO><<<dim3(8, 64, 1), blk256, 0, stream>>>(
        o_bf, HID_, 0, 0, 0, woT, HID_, 0, 0, 0, 0, 0, 0, HID_, a);
  }

  // 7) x2 = bf16(rms(h1, ln2_w)); router (fp32); balance loss scalar
  rmsnorm_cast_k<<<M_, blk256, 0, stream>>>(out, ln2w, x2_bf);
  router_k<<<M_ / 4, blk256, 0, stream>>>(out, ln2w, router_w, router_b, rwbuf);
  balance_k<<<1, blk256, 0, stream>>>(rwbuf, out + (size_t)M_ * HID_);

  // 8) dense MoE: fused dual-B GU (silu*u*rw folded) per expert on the
  //    4-phase kernel; expert-paired down via PAIRK K-concat (K=4096).
  const size_t wsz = (size_t)IM_ * HID_;
  if (paired) {
    for (int p = 0; p < 2; ++p) {
      const int e0 = 2 * p, e1 = e0 + 1;
      gemm4p_k<true, EPI4_GU, 1024, 1024, false><<<dim3(16, 32, 1), blk512, 0, stream>>>(
          x2_bf, nullptr, gateT + (size_t)e0 * wsz, upT + (size_t)e0 * wsz,
          rwbuf, e0, gu0, nullptr, nullptr);
      gemm4p_k<true, EPI4_GU, 1024, 1024, false><<<dim3(16, 32, 1), blk512, 0, stream>>>(
          x2_bf, nullptr, gateT + (size_t)e1 * wsz, upT + (size_t)e1 * wsz,
          rwbuf, e1, gu1, nullptr, nullptr);
      gemm4p_k<false, EPI4_DOWN, 4096, 2048, true><<<dim3(8, 32, 1), blk512, 0, stream>>>(
          gu0, gu1, downT + (size_t)e0 * wsz, downT + (size_t)e1 * wsz,
          nullptr, 0, nullptr, nullptr, out);
    }
  } else {
    for (int i = 0; i < E_; ++i) {
      gemm_dual_k<EPI2_GU><<<dim3(16, 64, 1), blk256, 0, stream>>>(
          x2_bf, gateT + (size_t)i * wsz, upT + (size_t)i * wsz, i, gu0, nullptr, rwbuf);
      EpiAux ad{}; ad.out2 = out;
      gemm_bf16k<EPI_DOWN><<<dim3(8, 64, 1), blk256, 0, stream>>>(
          gu0, IM_, 0, 0, 0, downT + (size_t)i * wsz, IM_, 0, 0, 0,
          0, 0, 0, IM_, ad);
    }
  }
}